// Round 23
// baseline (49.523 us; speedup 1.0000x reference)
//
#include <hip/hip_runtime.h>

#define N_RAYS     131072
#define MAX_STEPS  128
#define R2_CULL    0.65f     // sigma line-integral outside <= 7.4e-4 (verified R16)

// Identity barrier: forces the value through a VGPR via empty inline asm.
__device__ __forceinline__ float opq(float x) { asm("" : "+v"(x)); return x; }

// ---- prepass: strict slab + window; misses -> out=1; hits -> 48B entry ----
__global__ __launch_bounds__(256) void prepass_kernel(
    const float* __restrict__ raysO,
    const float* __restrict__ raysD,
    unsigned* __restrict__ counter,
    float4* __restrict__ entries,      // 3 float4 per ray
    float* __restrict__ out)
{
    #pragma clang fp contract(off)

    const int r = blockIdx.x * blockDim.x + threadIdx.x;
    if (r >= N_RAYS) return;

    const float ox = raysO[3*r+0], oy = raysO[3*r+1], oz = raysO[3*r+2];
    const float dx = raysD[3*r+0], dy = raysD[3*r+1], dz = raysD[3*r+2];

    // ---- slab: strict f32, recip-mult form (verified R12/R18) ----
    const float sdx = (fabsf(dx) > 1e-8f) ? dx : 1e-8f;
    const float sdy = (fabsf(dy) > 1e-8f) ? dy : 1e-8f;
    const float sdz = (fabsf(dz) > 1e-8f) ? dz : 1e-8f;
    const float rdx = opq(1.0f / sdx);
    const float rdy = opq(1.0f / sdy);
    const float rdz = opq(1.0f / sdz);
    const float t0x = opq(opq(-2.0f - ox) * rdx);
    const float t1x = opq(opq( 2.0f - ox) * rdx);
    const float t0y = opq(opq(-2.0f - oy) * rdy);
    const float t1y = opq(opq( 2.0f - oy) * rdy);
    const float t0z = opq(opq(-2.0f - oz) * rdz);
    const float t1z = opq(opq( 2.0f - oz) * rdz);
    const float tmin = fmaxf(fmaxf(fminf(t0x, t1x), fminf(t0y, t1y)), fminf(t0z, t1z));
    const float tmax = fminf(fminf(fmaxf(t0x, t1x), fmaxf(t0y, t1y)), fmaxf(t0z, t1z));
    const float nearT = fmaxf(tmin, 0.05f);
    const float farT  = fmaxf(tmax, opq(nearT + 1e-6f));
    const float dtv   = opq(opq(farT - nearT) * 0.0078125f);   // /128: pow2-exact

    // ---- blob culling (verified R13/R16) ----
    int s_lo = 0, s_hi = -1;
    {
        const float b    = ox*dx + oy*dy + oz*dz;
        const float c    = ox*ox + oy*oy + oz*oz - R2_CULL;
        const float disc = b*b - c;
        if (disc > 0.0f) {
            const float sq = sqrtf(disc) + 0.01f;
            const float inv_dt = 1.0f / dtv;
            float fs_lo = (-b - sq - nearT) * inv_dt - 0.5f;
            float fs_hi = (-b + sq - nearT) * inv_dt - 0.5f;
            fs_lo = fminf(fmaxf(fs_lo, -2.0f), 130.0f);
            fs_hi = fminf(fmaxf(fs_hi, -2.0f), 130.0f);
            s_lo = max(0, (int)floorf(fs_lo) - 1);
            s_hi = min(MAX_STEPS - 1, (int)ceilf(fs_hi) + 1);
        }
    }

    const int n = s_hi - s_lo + 1;
    const bool hit = (n > 0);

    // ---- wave-aggregated compaction (1 atomic per wave) ----
    const int lane = threadIdx.x & 63;
    const unsigned long long bal = __ballot(hit);
    if (hit) {
        const int leader   = (int)(__ffsll((long long)bal) - 1);
        const int lanerank = __popcll(bal & ((1ull << lane) - 1ull));
        unsigned base = 0;
        if (lane == leader) base = atomicAdd(counter, (unsigned)__popcll(bal));
        base = (unsigned)__shfl((int)base, leader);
        const unsigned slot = base + (unsigned)lanerank;

        entries[3*slot+0] = make_float4(ox, oy, oz, nearT);   // exact bits through
        entries[3*slot+1] = make_float4(dx, dy, dz, dtv);
        entries[3*slot+2] = make_float4(__int_as_float(s_lo), __int_as_float(n),
                                        __int_as_float(r), 0.0f);
    } else {
        // miss: ref deviates from 1.0 by <= sigma tail bound (verified regime)
        out[3*r+0] = 1.0f;
        out[3*r+1] = 1.0f;
        out[3*r+2] = 1.0f;
    }
}

// ---- march: 4 segments per compacted hit; verified R19/R21 step chain ----
__global__ __launch_bounds__(256, 8) void march_kernel(
    const float* __restrict__ grid,
    const unsigned* __restrict__ counter,
    const float4* __restrict__ entries,
    float* __restrict__ out)
{
    #pragma clang fp contract(off)

    const int tid  = blockIdx.x * blockDim.x + threadIdx.x;
    const int slot = tid >> 2;
    const int seg  = tid & 3;
    if ((unsigned)slot >= counter[0]) return;

    const float4 e0 = entries[3*slot+0];
    const float4 e1 = entries[3*slot+1];
    const float4 e2 = entries[3*slot+2];
    const float ox = e0.x, oy = e0.y, oz = e0.z, nearT = e0.w;
    const float dx = e1.x, dy = e1.y, dz = e1.z, dtv   = e1.w;
    const int s_lo = __float_as_int(e2.x);
    const int n    = __float_as_int(e2.y);
    const int r    = __float_as_int(e2.z);

    float T = 1.0f;
    float accR = 0.0f, accG = 0.0f, accB = 0.0f;
    float wsum = 0.0f;

    const float INV_2R2 = 1.0f / 0.08f;

    const int per = (n + 3) >> 2;
    const int lo  = s_lo + seg * per;
    const int hi  = min(lo + per - 1, s_lo + n - 1);

    #pragma unroll 8
    for (int s = lo; s <= hi; ++s) {
        // ---- verified per-step DECISION chain (bit-identical to R12) ----
        const float sp = opq((float)s + 0.5f);                 // exact
        const float t  = opq(__builtin_fmaf(sp, dtv, nearT));  // fused
        const float x  = opq(ox + opq(t * dx));                // strict
        const float y  = opq(oy + opq(t * dy));
        const float z  = opq(oz + opq(t * dz));

        const float ux = opq(opq(x * 0.5f) + 0.5f);            // cas=0 proven
        const float uy = opq(opq(y * 0.5f) + 0.5f);
        const float uz = opq(opq(z * 0.5f) + 0.5f);
        const int ixv = (int)opq(ux * 128.0f);                 // pow2-exact
        const int iyv = (int)opq(uy * 128.0f);
        const int izv = (int)opq(uz * 128.0f);

        const int gi = (ixv << 14) + (iyv << 7) + izv;         // cas 0
        const bool occ = grid[gi] > 10.0f;                     // exact compare

        // ---- continuous path (feeds no discrete decision) ----
        const float d2     = __builtin_fmaf(x, x, __builtin_fmaf(y, y, z * z));
        const float sigma0 = 5.0f * __expf(-(d2 * INV_2R2));
        const float sigma  = occ ? sigma0 : 0.0f;
        const float alpha  = 1.0f - __expf(-(sigma * dtv));
        const float w      = alpha * T;

        const float cr = __builtin_fmaf(x, 0.25f, 0.5f);       // clamp = identity
        const float cg = __builtin_fmaf(y, 0.25f, 0.5f);
        const float cb = __builtin_fmaf(z, 0.25f, 0.5f);

        accR = __builtin_fmaf(w, cr, accR);
        accG = __builtin_fmaf(w, cg, accG);
        accB = __builtin_fmaf(w, cb, accB);
        wsum += w;
        T *= (1.0f - alpha);
    }

    // ---- ordered associative combine across the 4 segment lanes ----
    const int lane = threadIdx.x & 63;
    #pragma unroll
    for (int m = 1; m <= 2; m <<= 1) {
        const float To  = __shfl_xor(T,    m);
        const float aRo = __shfl_xor(accR, m);
        const float aGo = __shfl_xor(accG, m);
        const float aBo = __shfl_xor(accB, m);
        const float wo  = __shfl_xor(wsum, m);
        const bool left = ((lane & m) == 0);
        const float Tf  = left ? T    : To;
        const float aR1 = left ? accR : aRo, aR2 = left ? aRo : accR;
        const float aG1 = left ? accG : aGo, aG2 = left ? aGo : accG;
        const float aB1 = left ? accB : aBo, aB2 = left ? aBo : accB;
        const float w1  = left ? wsum : wo,  w2  = left ? wo  : wsum;
        accR = aR1 + Tf * aR2;
        accG = aG1 + Tf * aG2;
        accB = aB1 + Tf * aB2;
        wsum = w1  + Tf * w2;
        T    = T * To;
    }

    if (seg == 0) {
        const float bg = 1.0f - wsum;   // bgColor = 1
        out[3*r+0] = accR + bg;
        out[3*r+1] = accG + bg;
        out[3*r+2] = accB + bg;
    }
}

// ---- fallback: R21 monolithic (if ws too small) ----
__global__ __launch_bounds__(256, 8) void renderer_mono(
    const float* __restrict__ raysO,
    const float* __restrict__ raysD,
    const float* __restrict__ grid,
    float* __restrict__ out)
{
    #pragma clang fp contract(off)
    const int tid = blockIdx.x * blockDim.x + threadIdx.x;
    const int r   = tid >> 2;
    const int seg = tid & 3;
    if (r >= N_RAYS) return;

    const float ox = raysO[3*r+0], oy = raysO[3*r+1], oz = raysO[3*r+2];
    const float dx = raysD[3*r+0], dy = raysD[3*r+1], dz = raysD[3*r+2];

    const float sdx = (fabsf(dx) > 1e-8f) ? dx : 1e-8f;
    const float sdy = (fabsf(dy) > 1e-8f) ? dy : 1e-8f;
    const float sdz = (fabsf(dz) > 1e-8f) ? dz : 1e-8f;
    const float rdx = opq(1.0f / sdx);
    const float rdy = opq(1.0f / sdy);
    const float rdz = opq(1.0f / sdz);
    const float t0x = opq(opq(-2.0f - ox) * rdx);
    const float t1x = opq(opq( 2.0f - ox) * rdx);
    const float t0y = opq(opq(-2.0f - oy) * rdy);
    const float t1y = opq(opq( 2.0f - oy) * rdy);
    const float t0z = opq(opq(-2.0f - oz) * rdz);
    const float t1z = opq(opq( 2.0f - oz) * rdz);
    const float tmin = fmaxf(fmaxf(fminf(t0x, t1x), fminf(t0y, t1y)), fminf(t0z, t1z));
    const float tmax = fminf(fminf(fmaxf(t0x, t1x), fmaxf(t0y, t1y)), fmaxf(t0z, t1z));
    const float nearT = fmaxf(tmin, 0.05f);
    const float farT  = fmaxf(tmax, opq(nearT + 1e-6f));
    const float dtv   = opq(opq(farT - nearT) * 0.0078125f);

    int s_lo = 0, s_hi = -1;
    {
        const float b    = ox*dx + oy*dy + oz*dz;
        const float c    = ox*ox + oy*oy + oz*oz - R2_CULL;
        const float disc = b*b - c;
        if (disc > 0.0f) {
            const float sq = sqrtf(disc) + 0.01f;
            const float inv_dt = 1.0f / dtv;
            float fs_lo = (-b - sq - nearT) * inv_dt - 0.5f;
            float fs_hi = (-b + sq - nearT) * inv_dt - 0.5f;
            fs_lo = fminf(fmaxf(fs_lo, -2.0f), 130.0f);
            fs_hi = fminf(fmaxf(fs_hi, -2.0f), 130.0f);
            s_lo = max(0, (int)floorf(fs_lo) - 1);
            s_hi = min(MAX_STEPS - 1, (int)ceilf(fs_hi) + 1);
        }
    }

    float T = 1.0f, accR = 0.0f, accG = 0.0f, accB = 0.0f, wsum = 0.0f;
    const float INV_2R2 = 1.0f / 0.08f;
    const int n = s_hi - s_lo + 1;
    if (n > 0) {
        const int per = (n + 3) >> 2;
        const int lo  = s_lo + seg * per;
        const int hi  = min(lo + per - 1, s_hi);
        #pragma unroll 8
        for (int s = lo; s <= hi; ++s) {
            const float sp = opq((float)s + 0.5f);
            const float t  = opq(__builtin_fmaf(sp, dtv, nearT));
            const float x  = opq(ox + opq(t * dx));
            const float y  = opq(oy + opq(t * dy));
            const float z  = opq(oz + opq(t * dz));
            const float ux = opq(opq(x * 0.5f) + 0.5f);
            const float uy = opq(opq(y * 0.5f) + 0.5f);
            const float uz = opq(opq(z * 0.5f) + 0.5f);
            const int ixv = (int)opq(ux * 128.0f);
            const int iyv = (int)opq(uy * 128.0f);
            const int izv = (int)opq(uz * 128.0f);
            const int gi = (ixv << 14) + (iyv << 7) + izv;
            const bool occ = grid[gi] > 10.0f;
            const float d2     = __builtin_fmaf(x, x, __builtin_fmaf(y, y, z * z));
            const float sigma0 = 5.0f * __expf(-(d2 * INV_2R2));
            const float sigma  = occ ? sigma0 : 0.0f;
            const float alpha  = 1.0f - __expf(-(sigma * dtv));
            const float w      = alpha * T;
            accR = __builtin_fmaf(w, __builtin_fmaf(x, 0.25f, 0.5f), accR);
            accG = __builtin_fmaf(w, __builtin_fmaf(y, 0.25f, 0.5f), accG);
            accB = __builtin_fmaf(w, __builtin_fmaf(z, 0.25f, 0.5f), accB);
            wsum += w;
            T *= (1.0f - alpha);
        }
    }

    const int lane = threadIdx.x & 63;
    #pragma unroll
    for (int m = 1; m <= 2; m <<= 1) {
        const float To  = __shfl_xor(T,    m);
        const float aRo = __shfl_xor(accR, m);
        const float aGo = __shfl_xor(accG, m);
        const float aBo = __shfl_xor(accB, m);
        const float wo  = __shfl_xor(wsum, m);
        const bool left = ((lane & m) == 0);
        const float Tf  = left ? T    : To;
        const float aR1 = left ? accR : aRo, aR2 = left ? aRo : accR;
        const float aG1 = left ? accG : aGo, aG2 = left ? aGo : accG;
        const float aB1 = left ? accB : aBo, aB2 = left ? aBo : accB;
        const float w1  = left ? wsum : wo,  w2  = left ? wo  : wsum;
        accR = aR1 + Tf * aR2; accG = aG1 + Tf * aG2; accB = aB1 + Tf * aB2;
        wsum = w1 + Tf * w2; T = T * To;
    }
    if (seg == 0) {
        const float bg = 1.0f - wsum;
        out[3*r+0] = accR + bg;
        out[3*r+1] = accG + bg;
        out[3*r+2] = accB + bg;
    }
}

extern "C" void kernel_launch(void* const* d_in, const int* in_sizes, int n_in,
                              void* d_out, int out_size, void* d_ws, size_t ws_size,
                              hipStream_t stream) {
    const float* raysO = (const float*)d_in[0];
    const float* raysD = (const float*)d_in[1];
    const float* grid  = (const float*)d_in[2];
    float* out = (float*)d_out;

    const int threads = 256;
    const size_t ws_needed = 64 + (size_t)N_RAYS * 48;

    if (ws_size >= ws_needed) {
        unsigned* counter = (unsigned*)d_ws;
        float4*   entries = (float4*)((char*)d_ws + 64);
        hipMemsetAsync(counter, 0, sizeof(unsigned), stream);
        prepass_kernel<<<N_RAYS / threads, threads, 0, stream>>>(raysO, raysD, counter, entries, out);
        const int total = N_RAYS * 4;
        march_kernel<<<(total + threads - 1) / threads, threads, 0, stream>>>(
            grid, counter, entries, out);
    } else {
        const int total = N_RAYS * 4;
        renderer_mono<<<(total + threads - 1) / threads, threads, 0, stream>>>(raysO, raysD, grid, out);
    }
}

// Round 24
// 18.305 us; speedup vs baseline: 2.7054x; 2.7054x over previous
//
#include <hip/hip_runtime.h>

#define N_RAYS     131072
#define MAX_STEPS  128
#define R2_CULL    0.65f     // sigma line-integral outside <= 7.4e-4 (verified R16)

// Identity barrier: forces the value through a VGPR via empty inline asm.
__device__ __forceinline__ float opq(float x) { asm("" : "+v"(x)); return x; }

__global__ __launch_bounds__(256, 8) void renderer_kernel(
    const float* __restrict__ raysO,
    const float* __restrict__ raysD,
    const float* __restrict__ grid,
    float* __restrict__ out)
{
    #pragma clang fp contract(off)

    const int tid = blockIdx.x * blockDim.x + threadIdx.x;
    const int r   = tid >> 2;          // ray index
    const int seg = tid & 3;           // segment 0..3
    if (r >= N_RAYS) return;

    const float ox = raysO[3*r+0], oy = raysO[3*r+1], oz = raysO[3*r+2];
    const float dx = raysD[3*r+0], dy = raysD[3*r+1], dz = raysD[3*r+2];

    // ---- slab: strict f32, recip-mult form (verified R12/R18) ----
    const float sdx = (fabsf(dx) > 1e-8f) ? dx : 1e-8f;
    const float sdy = (fabsf(dy) > 1e-8f) ? dy : 1e-8f;
    const float sdz = (fabsf(dz) > 1e-8f) ? dz : 1e-8f;
    const float rdx = opq(1.0f / sdx);
    const float rdy = opq(1.0f / sdy);
    const float rdz = opq(1.0f / sdz);
    const float t0x = opq(opq(-2.0f - ox) * rdx);
    const float t1x = opq(opq( 2.0f - ox) * rdx);
    const float t0y = opq(opq(-2.0f - oy) * rdy);
    const float t1y = opq(opq( 2.0f - oy) * rdy);
    const float t0z = opq(opq(-2.0f - oz) * rdz);
    const float t1z = opq(opq( 2.0f - oz) * rdz);
    const float tmin = fmaxf(fmaxf(fminf(t0x, t1x), fminf(t0y, t1y)), fminf(t0z, t1z));
    const float tmax = fminf(fminf(fmaxf(t0x, t1x), fmaxf(t0y, t1y)), fmaxf(t0z, t1z));
    const float nearT = fmaxf(tmin, 0.05f);
    const float farT  = fmaxf(tmax, opq(nearT + 1e-6f));
    const float dtv   = opq(opq(farT - nearT) * 0.0078125f);   // /128: pow2-exact

    // ---- blob culling (verified R13/R16) ----
    int s_lo = 0, s_hi = -1;
    {
        const float b    = ox*dx + oy*dy + oz*dz;
        const float c    = ox*ox + oy*oy + oz*oz - R2_CULL;
        const float disc = b*b - c;
        if (disc > 0.0f) {
            const float sq = sqrtf(disc) + 0.01f;
            const float inv_dt = 1.0f / dtv;
            float fs_lo = (-b - sq - nearT) * inv_dt - 0.5f;
            float fs_hi = (-b + sq - nearT) * inv_dt - 0.5f;
            fs_lo = fminf(fmaxf(fs_lo, -2.0f), 130.0f);
            fs_hi = fminf(fmaxf(fs_hi, -2.0f), 130.0f);
            s_lo = max(0, (int)floorf(fs_lo) - 1);
            s_hi = min(MAX_STEPS - 1, (int)ceilf(fs_hi) + 1);
        }
    }

    float T = 1.0f;
    float accR = 0.0f, accG = 0.0f, accB = 0.0f;
    float wsum = 0.0f;

    const float INV_2R2 = 1.0f / 0.08f;

    const int n = s_hi - s_lo + 1;
    if (n > 0) {
        const int per = (n + 3) >> 2;
        const int lo  = s_lo + seg * per;
        const int hi  = min(lo + per - 1, s_hi);

        // Two-phase strips of 8: batch-issue 8 gathers (phase 1), then consume
        // (phase 2). Tail clamps s to hi (redundant valid-address loads,
        // discarded via `valid`); iterated values bit-identical to R19.
        for (int sb = lo; sb <= hi; sb += 8) {
            float xs[8], ys[8], zs[8], gvv[8];

            #pragma unroll
            for (int j = 0; j < 8; ++j) {
                const int s = min(sb + j, hi);                     // clamp tail
                // ---- verified per-step DECISION chain (bit-identical R12) ----
                const float sp = opq((float)s + 0.5f);             // exact
                const float t  = opq(__builtin_fmaf(sp, dtv, nearT)); // fused
                const float x  = opq(ox + opq(t * dx));            // strict
                const float y  = opq(oy + opq(t * dy));
                const float z  = opq(oz + opq(t * dz));

                const float ux = opq(opq(x * 0.5f) + 0.5f);        // cas=0 proven
                const float uy = opq(opq(y * 0.5f) + 0.5f);
                const float uz = opq(opq(z * 0.5f) + 0.5f);
                const int ixv = (int)opq(ux * 128.0f);             // pow2-exact
                const int iyv = (int)opq(uy * 128.0f);
                const int izv = (int)opq(uz * 128.0f);

                xs[j] = x; ys[j] = y; zs[j] = z;
                gvv[j] = grid[(ixv << 14) + (iyv << 7) + izv];     // cas 0
            }

            #pragma unroll
            for (int j = 0; j < 8; ++j) {
                const bool valid = (sb + j) <= hi;
                const bool occ   = valid && (gvv[j] > 10.0f);      // exact compare
                const float x = xs[j], y = ys[j], z = zs[j];

                // ---- continuous path (feeds no discrete decision) ----
                const float d2     = __builtin_fmaf(x, x, __builtin_fmaf(y, y, z * z));
                const float sigma0 = 5.0f * __expf(-(d2 * INV_2R2));
                const float sigma  = occ ? sigma0 : 0.0f;
                const float alpha  = 1.0f - __expf(-(sigma * dtv));
                const float w      = alpha * T;

                const float cr = __builtin_fmaf(x, 0.25f, 0.5f);   // clamp=identity
                const float cg = __builtin_fmaf(y, 0.25f, 0.5f);
                const float cb = __builtin_fmaf(z, 0.25f, 0.5f);

                accR = __builtin_fmaf(w, cr, accR);
                accG = __builtin_fmaf(w, cg, accG);
                accB = __builtin_fmaf(w, cb, accB);
                wsum += w;
                T *= (1.0f - alpha);
            }
        }
    }

    // ---- ordered associative combine across the 4 segment lanes ----
    const int lane = threadIdx.x & 63;
    #pragma unroll
    for (int m = 1; m <= 2; m <<= 1) {
        const float To  = __shfl_xor(T,    m);
        const float aRo = __shfl_xor(accR, m);
        const float aGo = __shfl_xor(accG, m);
        const float aBo = __shfl_xor(accB, m);
        const float wo  = __shfl_xor(wsum, m);
        const bool left = ((lane & m) == 0);
        const float Tf  = left ? T    : To;
        const float aR1 = left ? accR : aRo, aR2 = left ? aRo : accR;
        const float aG1 = left ? accG : aGo, aG2 = left ? aGo : accG;
        const float aB1 = left ? accB : aBo, aB2 = left ? aBo : accB;
        const float w1  = left ? wsum : wo,  w2  = left ? wo  : wsum;
        accR = aR1 + Tf * aR2;
        accG = aG1 + Tf * aG2;
        accB = aB1 + Tf * aB2;
        wsum = w1  + Tf * w2;
        T    = T * To;
    }

    if (seg == 0) {
        const float bg = 1.0f - wsum;   // bgColor = 1
        out[3*r+0] = accR + bg;
        out[3*r+1] = accG + bg;
        out[3*r+2] = accB + bg;
    }
}

extern "C" void kernel_launch(void* const* d_in, const int* in_sizes, int n_in,
                              void* d_out, int out_size, void* d_ws, size_t ws_size,
                              hipStream_t stream) {
    const float* raysO = (const float*)d_in[0];
    const float* raysD = (const float*)d_in[1];
    const float* grid  = (const float*)d_in[2];
    float* out = (float*)d_out;

    const int threads = 256;
    const int total   = N_RAYS * 4;                      // 4 segments per ray
    const int blocks  = (total + threads - 1) / threads; // 2048
    renderer_kernel<<<blocks, threads, 0, stream>>>(raysO, raysD, grid, out);
}